// Round 1
// baseline (139.011 us; speedup 1.0000x reference)
//
#include <hip/hip_runtime.h>
#include <math.h>

#define N_STEPS 65536
#define N_DIMS  512
#define T_CHUNK 128
#define N_CHUNKS (N_STEPS / T_CHUNK)   // 512

// h_t = g_t * h_{t-1} + b_t ;  g = sigmoid(gate_raw), b = (1-g)*relu(impulse_raw)
// combine((a1,b1),(a2,b2)) = (a1*a2, a2*b1 + b2)   (c1 earlier in time)

__device__ __forceinline__ void step_gb(float graw, float iraw, float& g, float& b) {
    g = 1.0f / (1.0f + __expf(-graw));
    b = (1.0f - g) * fmaxf(iraw, 0.0f);
}

// Phase 1: per-chunk reduction -> (A = prod g, B = response at chunk end with h_in = 0)
__global__ __launch_bounds__(256) void gilr_phase1(const float* __restrict__ x,
                                                   float* __restrict__ wsA,
                                                   float* __restrict__ wsB) {
    const int c = blockIdx.x;
    const int d = threadIdx.x * 2;
    const float2* gptr = (const float2*)(x + (size_t)c * T_CHUNK * N_DIMS + d);
    const float2* iptr = (const float2*)(x + ((size_t)N_STEPS + (size_t)c * T_CHUNK) * N_DIMS + d);
    float Ax = 1.0f, Ay = 1.0f, Bx = 0.0f, By = 0.0f;
    #pragma unroll 4
    for (int t = 0; t < T_CHUNK; ++t) {
        float2 graw = gptr[t * (N_DIMS / 2)];
        float2 iraw = iptr[t * (N_DIMS / 2)];
        float g0, b0, g1, b1;
        step_gb(graw.x, iraw.x, g0, b0);
        step_gb(graw.y, iraw.y, g1, b1);
        Ax *= g0;  Ay *= g1;
        Bx = g0 * Bx + b0;  By = g1 * By + b1;
    }
    *(float2*)(wsA + (size_t)c * N_DIMS + d) = make_float2(Ax, Ay);
    *(float2*)(wsB + (size_t)c * N_DIMS + d) = make_float2(Bx, By);
}

// Phase 2: one block per dim; Hillis-Steele inclusive scan over the N_CHUNKS
// aggregates in LDS; write carry-in h for every chunk.
__global__ __launch_bounds__(N_CHUNKS) void gilr_phase2(const float* __restrict__ wsA,
                                                        const float* __restrict__ wsB,
                                                        float* __restrict__ carry) {
    const int d = blockIdx.x;
    const int c = threadIdx.x;           // 0..N_CHUNKS-1
    __shared__ float sA[N_CHUNKS];
    __shared__ float sB[N_CHUNKS];
    float a = wsA[(size_t)c * N_DIMS + d];
    float b = wsB[(size_t)c * N_DIMS + d];
    sA[c] = a; sB[c] = b;
    __syncthreads();
    for (int off = 1; off < N_CHUNKS; off <<= 1) {
        float pa = 1.0f, pb = 0.0f;
        const bool has = (c >= off);
        if (has) { pa = sA[c - off]; pb = sB[c - off]; }
        __syncthreads();
        if (has) {
            b = a * pb + b;      // combine(prev, cur): B = A_cur*B_prev + B_cur
            a = a * pa;          //                     A = A_prev*A_cur
            sA[c] = a; sB[c] = b;
        }
        __syncthreads();
    }
    // carry into chunk c = inclusive scan result of chunk c-1 (B part); 0 for c==0
    const float h_in = (c == 0) ? 0.0f : sB[c - 1];
    carry[(size_t)c * N_DIMS + d] = h_in;
}

// Phase 3: re-read x, run recurrence from carry, write full response.
__global__ __launch_bounds__(256) void gilr_phase3(const float* __restrict__ x,
                                                   const float* __restrict__ carry,
                                                   float* __restrict__ out) {
    const int c = blockIdx.x;
    const int d = threadIdx.x * 2;
    const float2* gptr = (const float2*)(x + (size_t)c * T_CHUNK * N_DIMS + d);
    const float2* iptr = (const float2*)(x + ((size_t)N_STEPS + (size_t)c * T_CHUNK) * N_DIMS + d);
    float2* optr = (float2*)(out + (size_t)c * T_CHUNK * N_DIMS + d);
    float2 h = *(const float2*)(carry + (size_t)c * N_DIMS + d);
    #pragma unroll 4
    for (int t = 0; t < T_CHUNK; ++t) {
        float2 graw = gptr[t * (N_DIMS / 2)];
        float2 iraw = iptr[t * (N_DIMS / 2)];
        float g0, b0, g1, b1;
        step_gb(graw.x, iraw.x, g0, b0);
        step_gb(graw.y, iraw.y, g1, b1);
        h.x = g0 * h.x + b0;
        h.y = g1 * h.y + b1;
        optr[t * (N_DIMS / 2)] = h;
    }
}

extern "C" void kernel_launch(void* const* d_in, const int* in_sizes, int n_in,
                              void* d_out, int out_size, void* d_ws, size_t ws_size,
                              hipStream_t stream) {
    const float* x = (const float*)d_in[0];
    float* out = (float*)d_out;
    float* wsA   = (float*)d_ws;
    float* wsB   = wsA + (size_t)N_CHUNKS * N_DIMS;
    float* carry = wsB + (size_t)N_CHUNKS * N_DIMS;

    gilr_phase1<<<N_CHUNKS, 256, 0, stream>>>(x, wsA, wsB);
    gilr_phase2<<<N_DIMS, N_CHUNKS, 0, stream>>>(wsA, wsB, carry);
    gilr_phase3<<<N_CHUNKS, 256, 0, stream>>>(x, carry, out);
}